// Round 5
// baseline (213.126 us; speedup 1.0000x reference)
//
#include <hip/hip_runtime.h>

// Circle loss with hard mining, fused flash-style. N=4096, D=512, 64 classes.
// ws layout: [0,4MB) x_bf16 normalized; [4MB,+8) {loss_sum, valid_cnt}.
// k_main4: 16 rows/block, 512 threads (8 waves = 2/EU min -> 256-VGPR cap).
// A tile in LDS; B fragments PING-PONG PREFETCHED in registers (2x64 VGPR)
// so tile t+1's 16 loads are in flight during tile t's MFMA+lse.

#define GAMMA_ 256.0f
#define OP_ 1.25f
#define ON_ (-0.25f)
#define DP_ 0.75f
#define DN_ 0.25f
#define MASKT_ (-1.0e4f)   // masked term; running max m>=0 => exp(MASKT-m)==0

constexpr int N_ = 4096;
constexpr int D_ = 512;
constexpr int AST_ = 520;  // A LDS row stride in shorts: 1040B -> 2-way bank alias only (free)

typedef __bf16 bf16x8 __attribute__((ext_vector_type(8)));
typedef float  f32x4  __attribute__((ext_vector_type(4)));

__device__ __forceinline__ float pos_term(float s) {
    return -GAMMA_ * fmaxf(OP_ - s, 0.0f) * (s - DP_);
}
__device__ __forceinline__ float neg_term(float s) {
    return  GAMMA_ * fmaxf(s - ON_, 0.0f) * (s - DN_);
}
__device__ __forceinline__ void lse_merge(float m2, float S2, float& m, float& S) {
    float mm = fmaxf(m, m2);
    S = S * __expf(m - mm) + S2 * __expf(m2 - mm);
    m = mm;
}
__device__ __forceinline__ unsigned short f2bf(float f) {  // RNE
    unsigned int u = __float_as_uint(f);
    unsigned int r = u + 0x7FFFu + ((u >> 16) & 1u);
    return (unsigned short)(r >> 16);
}

// ---- kernel 1: L2 normalize rows, cast to bf16; block 0 zeroes the accumulators ----
__global__ __launch_bounds__(256) void k_norm(const float* __restrict__ in,
                                              unsigned short* __restrict__ xb,
                                              float* __restrict__ acc) {
    const int row  = blockIdx.x * 4 + (threadIdx.x >> 6);
    const int lane = threadIdx.x & 63;
    const float4* src = (const float4*)(in + (size_t)row * D_) + lane * 2;
    float4 a = src[0], b = src[1];
    float ss = a.x*a.x + a.y*a.y + a.z*a.z + a.w*a.w
             + b.x*b.x + b.y*b.y + b.z*b.z + b.w*b.w;
    #pragma unroll
    for (int d = 32; d >= 1; d >>= 1) ss += __shfl_xor(ss, d);
    float rn = 1.0f / sqrtf(ss);
    float v[8] = {a.x, a.y, a.z, a.w, b.x, b.y, b.z, b.w};
    union { uint4 u; unsigned short us[8]; } pk;
    #pragma unroll
    for (int k = 0; k < 8; ++k) pk.us[k] = f2bf(v[k] * rn);
    *((uint4*)(xb + (size_t)row * D_) + lane) = pk.u;
    if (blockIdx.x == 0 && threadIdx.x < 2) acc[threadIdx.x] = 0.0f;
}

// ---- kernel 2: 16 rows/block, 8 waves split 256 j-tiles, register prefetch ----
__global__ __launch_bounds__(512, 2) void k_main4(const unsigned short* __restrict__ xb,
                                                  const int* __restrict__ tg,
                                                  float* __restrict__ acc_g) {
    __shared__ __align__(16) unsigned short As[16 * AST_];
    __shared__ float sm[8][16][8];
    const int tid  = threadIdx.x;
    const int wave = tid >> 6, lane = tid & 63;
    const int n16  = lane & 15, quad = lane >> 4;
    const int rowBase = blockIdx.x * 16;

    // stage A tile (16 rows x 512 shorts = 1024 uint4) with 512 threads x2
    #pragma unroll
    for (int p = 0; p < 2; ++p) {
        int idx = tid + p * 512;
        int row = idx >> 6, c = idx & 63;
        *(uint4*)&As[row * AST_ + c * 8] =
            *(const uint4*)(xb + (size_t)(rowBase + row) * D_ + c * 8);
    }
    int ir[4], tr[4];
    #pragma unroll
    for (int r = 0; r < 4; ++r) { ir[r] = rowBase + quad * 4 + r; tr[r] = tg[ir[r]]; }

    float m_p[4], S_p[4], m_n[4], S_n[4], mnp[4], mxn[4], sc[4];
    #pragma unroll
    for (int r = 0; r < 4; ++r) {
        m_p[r] = 0.f; S_p[r] = 0.f; m_n[r] = 0.f; S_n[r] = 0.f;
        mnp[r] = 2.0f; mxn[r] = -2.0f; sc[r] = 0.f;
    }
    __syncthreads();

    const unsigned short* Af = &As[n16 * AST_ + quad * 8];

    // wave handles tiles t = i*8 + wave, i = 0..31 (32 of the 256 j-tiles)
    bf16x8 b0[16], b1[16];
    int tc0, tc1;

    auto prefetch = [&](int i, bf16x8 (&bfr)[16], int& tc) {
        int ii = (i < 32) ? i : 31;                 // clamped overrun prefetch
        int jcol = (ii * 8 + wave) * 16 + n16;
        const bf16x8* bp = (const bf16x8*)(xb + (size_t)jcol * D_ + quad * 8);
        #pragma unroll
        for (int kk = 0; kk < 16; ++kk) bfr[kk] = bp[kk * 4];  // 16 loads in flight
        tc = tg[jcol];
    };
    auto compute = [&](bf16x8 (&bfr)[16], int tc, int jcol) {
        f32x4 a0 = {0.f, 0.f, 0.f, 0.f}, a1 = {0.f, 0.f, 0.f, 0.f};
        #pragma unroll
        for (int kk = 0; kk < 8; ++kk) {
            bf16x8 af0 = *(const bf16x8*)(Af + (2 * kk) * 32);
            bf16x8 af1 = *(const bf16x8*)(Af + (2 * kk + 1) * 32);
            a0 = __builtin_amdgcn_mfma_f32_16x16x32_bf16(af0, bfr[2 * kk],     a0, 0, 0, 0);
            a1 = __builtin_amdgcn_mfma_f32_16x16x32_bf16(af1, bfr[2 * kk + 1], a1, 0, 0, 0);
        }
        #pragma unroll
        for (int r = 0; r < 4; ++r) {
            float s = a0[r] + a1[r];                  // sim[ir[r]][jcol]
            bool samec = (tr[r] == tc);
            bool posm  = samec && (jcol != ir[r]);
            float tp = posm  ? pos_term(s) : MASKT_;
            float tn = samec ? MASKT_ : neg_term(s);
            float mm = fmaxf(m_p[r], tp);             // branchless online lse
            S_p[r] = S_p[r] * __expf(m_p[r] - mm) + __expf(tp - mm); m_p[r] = mm;
            mm = fmaxf(m_n[r], tn);
            S_n[r] = S_n[r] * __expf(m_n[r] - mm) + __expf(tn - mm); m_n[r] = mm;
            sc[r] += samec ? 1.0f : 0.0f;             // npos = sc-1, nneg = N-sc
            mnp[r] = fminf(mnp[r], posm ? s : 2.0f);
            mxn[r] = fmaxf(mxn[r], samec ? -2.0f : s);
        }
    };

    prefetch(0, b0, tc0);
    #pragma unroll 1
    for (int i = 0; i < 32; i += 2) {
        prefetch(i + 1, b1, tc1);                     // in flight during compute(b0)
        compute(b0, tc0, (i * 8 + wave) * 16 + n16);
        prefetch(i + 2, b0, tc0);                     // in flight during compute(b1)
        compute(b1, tc1, ((i + 1) * 8 + wave) * 16 + n16);
    }

    // merge across the 16 lanes holding each row
    #pragma unroll
    for (int r = 0; r < 4; ++r) {
        #pragma unroll
        for (int d = 1; d <= 8; d <<= 1) {
            lse_merge(__shfl_xor(m_p[r], d), __shfl_xor(S_p[r], d), m_p[r], S_p[r]);
            lse_merge(__shfl_xor(m_n[r], d), __shfl_xor(S_n[r], d), m_n[r], S_n[r]);
            mnp[r] = fminf(mnp[r], __shfl_xor(mnp[r], d));
            mxn[r] = fmaxf(mxn[r], __shfl_xor(mxn[r], d));
            sc[r] += __shfl_xor(sc[r], d);
        }
    }
    if (n16 == 0) {
        #pragma unroll
        for (int r = 0; r < 4; ++r) {
            float* q = sm[wave][quad * 4 + r];
            q[0] = m_p[r]; q[1] = S_p[r]; q[2] = m_n[r]; q[3] = S_n[r];
            q[4] = mnp[r]; q[5] = mxn[r]; q[6] = sc[r];
        }
    }
    __syncthreads();

    if (tid < 64) {                      // wave 0 finalizes the 16 rows
        const int L = tid & 15;
        float m_p2 = 0.f, S_p2 = 0.f, m_n2 = 0.f, S_n2 = 0.f;
        float mnp2 = 2.0f, mxn2 = -2.0f, sct = 0.f;
        #pragma unroll
        for (int w = 0; w < 8; ++w) {
            const float* q = sm[w][L];
            lse_merge(q[0], q[1], m_p2, S_p2);
            lse_merge(q[2], q[3], m_n2, S_n2);
            mnp2 = fminf(mnp2, q[4]); mxn2 = fmaxf(mxn2, q[5]);
            sct += q[6];
        }
        float loss = 0.f, vld = 0.f;
        float np2 = sct - 1.0f, nn2 = (float)N_ - sct;
        if (tid < 16 && np2 > 0.5f && nn2 > 0.5f) {
            if (np2 > 1.5f) {            // hard positive: term exactly doubles
                float t1 = pos_term(mnp2), t2 = 2.0f * t1;
                float mm = fmaxf(m_p2, t2);
                S_p2 = S_p2 * __expf(m_p2 - mm) + __expf(t2 - mm) - __expf(t1 - mm);
                m_p2 = mm;
            }
            if (nn2 > 1.5f) {
                float t1 = neg_term(mxn2), t2 = 2.0f * t1;
                float mm = fmaxf(m_n2, t2);
                S_n2 = S_n2 * __expf(m_n2 - mm) + __expf(t2 - mm) - __expf(t1 - mm);
                m_n2 = mm;
            }
            float z = (m_p2 + __logf(S_p2)) + (m_n2 + __logf(S_n2));
            loss = fmaxf(z, 0.0f) + log1pf(__expf(-fabsf(z)));   // softplus
            vld = 1.0f;
        }
        #pragma unroll
        for (int d = 32; d >= 1; d >>= 1) {
            loss += __shfl_xor(loss, d); vld += __shfl_xor(vld, d);
        }
        if (tid == 0) { atomicAdd(&acc_g[0], loss); atomicAdd(&acc_g[1], vld); }
    }
}

__global__ void k_final(const float* __restrict__ acc, float* __restrict__ out) {
    if (threadIdx.x == 0) out[0] = acc[0] / fmaxf(acc[1], 1.0f);
}

__global__ void k_sentinel(float* __restrict__ out) {
    if (threadIdx.x == 0) out[0] = -12345.0f;   // signals: ws_size < 4MB+64
}

extern "C" void kernel_launch(void* const* d_in, const int* in_sizes, int n_in,
                              void* d_out, int out_size, void* d_ws, size_t ws_size,
                              hipStream_t stream) {
    const float* in = (const float*)d_in[0];
    const int*   tg = (const int*)d_in[1];

    if (ws_size < (size_t)4 * 1024 * 1024 + 64) {
        hipLaunchKernelGGL(k_sentinel, dim3(1), dim3(64), 0, stream, (float*)d_out);
        return;
    }
    unsigned short* xb  = (unsigned short*)d_ws;
    float*          acc = (float*)((char*)d_ws + (size_t)4 * 1024 * 1024);

    hipLaunchKernelGGL(k_norm,  dim3(N_ / 4),  dim3(256), 0, stream, in, xb, acc);
    hipLaunchKernelGGL(k_main4, dim3(N_ / 16), dim3(512), 0, stream, xb, tg, acc);
    hipLaunchKernelGGL(k_final, dim3(1),       dim3(64),  0, stream, acc, (float*)d_out);
}

// Round 7
// 113.585 us; speedup vs baseline: 1.8763x; 1.8763x over previous
//
#include <hip/hip_runtime.h>

// Circle loss with hard mining, fused flash-style. N=4096, D=512, 64 classes.
// ws: [0,4MB) x_bf16 normalized; [4MB,5MB) partials (4096 rows x 8 chunks x 32B);
//     [5MB,+8) {loss_sum, valid_cnt}.
// k_mainB: 1-D grid 512 = 64 row-groups x 8 col-chunks. 256 thr = 4 waves x 16
// disjoint rows; 64 rows x 512 cols per block. B double-buffered in LDS via
// tiny 4xuint4 register staging, 1 barrier/stage; A register-resident.
// No templates / 2-D grids / tickets (R1+R6 abort suspects). Fallback: R4 path.

#define GAMMA_ 256.0f
#define OP_ 1.25f
#define ON_ (-0.25f)
#define DP_ 0.75f
#define DN_ 0.25f
#define MASKT_ (-1.0e4f)   // masked term; running max m>=0 => exp(MASKT-m)==0

constexpr int N_ = 4096;
constexpr int D_ = 512;
constexpr int AST_ = 520;  // padded LDS row stride (shorts)
constexpr int CCH_ = 8;    // col chunks

typedef __bf16 bf16x8 __attribute__((ext_vector_type(8)));
typedef float  f32x4  __attribute__((ext_vector_type(4)));

__device__ __forceinline__ float pos_term(float s) {
    return -GAMMA_ * fmaxf(OP_ - s, 0.0f) * (s - DP_);
}
__device__ __forceinline__ float neg_term(float s) {
    return  GAMMA_ * fmaxf(s - ON_, 0.0f) * (s - DN_);
}
__device__ __forceinline__ void lse_merge(float m2, float S2, float& m, float& S) {
    float mm = fmaxf(m, m2);
    S = S * __expf(m - mm) + S2 * __expf(m2 - mm);
    m = mm;
}
__device__ __forceinline__ unsigned short f2bf(float f) {  // RNE
    unsigned int u = __float_as_uint(f);
    unsigned int r = u + 0x7FFFu + ((u >> 16) & 1u);
    return (unsigned short)(r >> 16);
}

// ---- kernel 1: L2 normalize rows, cast to bf16; block 0 zeroes accumulators ----
__global__ __launch_bounds__(256) void k_norm(const float* __restrict__ in,
                                              unsigned short* __restrict__ xb,
                                              float* __restrict__ acc) {
    const int row  = blockIdx.x * 4 + (threadIdx.x >> 6);
    const int lane = threadIdx.x & 63;
    const float4* src = (const float4*)(in + (size_t)row * D_) + lane * 2;
    float4 a = src[0], b = src[1];
    float ss = a.x*a.x + a.y*a.y + a.z*a.z + a.w*a.w
             + b.x*b.x + b.y*b.y + b.z*b.z + b.w*b.w;
    #pragma unroll
    for (int d = 32; d >= 1; d >>= 1) ss += __shfl_xor(ss, d);
    float rn = 1.0f / sqrtf(ss);
    float v[8] = {a.x, a.y, a.z, a.w, b.x, b.y, b.z, b.w};
    union { uint4 u; unsigned short us[8]; } pk;
    #pragma unroll
    for (int k = 0; k < 8; ++k) pk.us[k] = f2bf(v[k] * rn);
    *((uint4*)(xb + (size_t)row * D_) + lane) = pk.u;
    if (blockIdx.x == 0 && threadIdx.x < 2) acc[threadIdx.x] = 0.0f;
}

// ---- main kernel B: 1-D grid 512; 64 rows x 512 cols per block ----
__global__ __launch_bounds__(256, 3) void k_mainB(const unsigned short* __restrict__ xb,
                                                  const int* __restrict__ tg,
                                                  float* __restrict__ part) {
    constexpr int COLS = N_ / CCH_;      // 512 cols per block
    constexpr int NST  = COLS / 16;      // 32 stages
    __shared__ __align__(16) unsigned short Bs[2][16][AST_];

    const int tid  = threadIdx.x;
    const int wave = tid >> 6, lane = tid & 63;
    const int n16  = lane & 15, quad = lane >> 4;
    const int rg   = (int)blockIdx.x >> 3;      // row group 0..63
    const int cc   = (int)blockIdx.x & 7;       // col chunk 0..7
    const int rowBase = rg * 64 + wave * 16;    // this wave's 16 rows
    const int colBase = cc * COLS;

    // A fragments: lane holds A[m=n16][k = quad*8 + kk*32 .. +8] (loop-invariant)
    bf16x8 af[16];
    {
        const bf16x8* ap = (const bf16x8*)(xb + (size_t)(rowBase + n16) * D_ + quad * 8);
        #pragma unroll
        for (int kk = 0; kk < 16; ++kk) af[kk] = ap[kk * 4];
    }
    int ir[4], tr[4];
    #pragma unroll
    for (int r = 0; r < 4; ++r) { ir[r] = rowBase + quad * 4 + r; tr[r] = tg[ir[r]]; }

    float m_p[4], S_p[4], m_n[4], S_n[4], mnp[4], mxn[4], sc[4];
    #pragma unroll
    for (int r = 0; r < 4; ++r) {
        m_p[r] = 0.f; S_p[r] = 0.f; m_n[r] = 0.f; S_n[r] = 0.f;
        mnp[r] = 2.0f; mxn[r] = -2.0f; sc[r] = 0.f;
    }

    // tiny register staging: 4 uint4/thread (16 VGPRs)
    uint4 pf0, pf1, pf2, pf3; int pftc;
    {
        const uint4* g = (const uint4*)(xb + (size_t)colBase * D_);
        pf0 = g[tid]; pf1 = g[256 + tid]; pf2 = g[512 + tid]; pf3 = g[768 + tid];
        pftc = tg[colBase + n16];
    }

    #pragma unroll 1
    for (int s = 0; s < NST; ++s) {
        const int b = s & 1;
        const int j0 = colBase + s * 16;
        {   // commit prefetched stage s into LDS buffer b
            int q;
            q = tid;       *(uint4*)&Bs[b][q >> 6][(q & 63) * 8] = pf0;
            q = 256 + tid; *(uint4*)&Bs[b][q >> 6][(q & 63) * 8] = pf1;
            q = 512 + tid; *(uint4*)&Bs[b][q >> 6][(q & 63) * 8] = pf2;
            q = 768 + tid; *(uint4*)&Bs[b][q >> 6][(q & 63) * 8] = pf3;
        }
        const int tc = pftc;
        if (s + 1 < NST) {               // loads for s+1 in flight during compute(s)
            const uint4* g = (const uint4*)(xb + (size_t)(j0 + 16) * D_);
            pf0 = g[tid]; pf1 = g[256 + tid]; pf2 = g[512 + tid]; pf3 = g[768 + tid];
            pftc = tg[j0 + 16 + n16];
        }
        __syncthreads();                 // buffer b visible to all waves

        f32x4 a0 = {0.f, 0.f, 0.f, 0.f}, a1 = {0.f, 0.f, 0.f, 0.f};
        #pragma unroll
        for (int kk = 0; kk < 8; ++kk) {
            bf16x8 bf0 = *(const bf16x8*)&Bs[b][n16][(2 * kk) * 32 + quad * 8];
            bf16x8 bf1 = *(const bf16x8*)&Bs[b][n16][(2 * kk + 1) * 32 + quad * 8];
            a0 = __builtin_amdgcn_mfma_f32_16x16x32_bf16(af[2 * kk],     bf0, a0, 0, 0, 0);
            a1 = __builtin_amdgcn_mfma_f32_16x16x32_bf16(af[2 * kk + 1], bf1, a1, 0, 0, 0);
        }

        const int jcol = j0 + n16;
        #pragma unroll
        for (int r = 0; r < 4; ++r) {
            float s_ = a0[r] + a1[r];                 // sim[ir[r]][jcol]
            bool samec = (tr[r] == tc);
            bool posm  = samec && (jcol != ir[r]);
            float tp = posm  ? pos_term(s_) : MASKT_;
            float tn = samec ? MASKT_ : neg_term(s_);
            float mm = fmaxf(m_p[r], tp);             // branchless online lse
            S_p[r] = S_p[r] * __expf(m_p[r] - mm) + __expf(tp - mm); m_p[r] = mm;
            mm = fmaxf(m_n[r], tn);
            S_n[r] = S_n[r] * __expf(m_n[r] - mm) + __expf(tn - mm); m_n[r] = mm;
            sc[r] += samec ? 1.0f : 0.0f;             // npos = sc-1, nneg = N-sc
            mnp[r] = fminf(mnp[r], posm ? s_ : 2.0f);
            mxn[r] = fmaxf(mxn[r], samec ? -2.0f : s_);
        }
    }

    // merge across the 16 lanes holding each row (waves own disjoint rows)
    #pragma unroll
    for (int r = 0; r < 4; ++r) {
        #pragma unroll
        for (int d = 1; d <= 8; d <<= 1) {
            lse_merge(__shfl_xor(m_p[r], d), __shfl_xor(S_p[r], d), m_p[r], S_p[r]);
            lse_merge(__shfl_xor(m_n[r], d), __shfl_xor(S_n[r], d), m_n[r], S_n[r]);
            mnp[r] = fminf(mnp[r], __shfl_xor(mnp[r], d));
            mxn[r] = fmaxf(mxn[r], __shfl_xor(mxn[r], d));
            sc[r] += __shfl_xor(sc[r], d);
        }
    }
    if (n16 == 0) {
        #pragma unroll
        for (int r = 0; r < 4; ++r) {
            float4* P = (float4*)part + ((size_t)ir[r] * CCH_ + cc) * 2;
            P[0] = make_float4(m_p[r], S_p[r], m_n[r], S_n[r]);
            P[1] = make_float4(mnp[r], mxn[r], sc[r], 0.0f);
        }
    }
}

// ---- reduce: merge 8 chunks/row, hard-mining fix, softplus, atomic fold ----
__global__ __launch_bounds__(256) void k_reduceB(const float* __restrict__ part,
                                                 float* __restrict__ acc) {
    const int row = blockIdx.x * 256 + threadIdx.x;
    const float4* P = (const float4*)part + (size_t)row * CCH_ * 2;
    float m_p = 0.f, S_p = 0.f, m_n = 0.f, S_n = 0.f;
    float mnp = 2.0f, mxn = -2.0f, sct = 0.f;
    #pragma unroll
    for (int c = 0; c < CCH_; ++c) {
        float4 a = P[2 * c], b = P[2 * c + 1];
        lse_merge(a.x, a.y, m_p, S_p);
        lse_merge(a.z, a.w, m_n, S_n);
        mnp = fminf(mnp, b.x); mxn = fmaxf(mxn, b.y); sct += b.z;
    }
    float loss = 0.f, vld = 0.f;
    float np2 = sct - 1.0f, nn2 = (float)N_ - sct;
    if (np2 > 0.5f && nn2 > 0.5f) {
        if (np2 > 1.5f) {                // hard positive: term exactly doubles
            float t1 = pos_term(mnp), t2 = 2.0f * t1;
            float mm = fmaxf(m_p, t2);
            S_p = S_p * __expf(m_p - mm) + __expf(t2 - mm) - __expf(t1 - mm);
            m_p = mm;
        }
        if (nn2 > 1.5f) {
            float t1 = neg_term(mxn), t2 = 2.0f * t1;
            float mm = fmaxf(m_n, t2);
            S_n = S_n * __expf(m_n - mm) + __expf(t2 - mm) - __expf(t1 - mm);
            m_n = mm;
        }
        float z = (m_p + __logf(S_p)) + (m_n + __logf(S_n));
        loss = fmaxf(z, 0.0f) + log1pf(__expf(-fabsf(z)));   // softplus
        vld = 1.0f;
    }
    #pragma unroll
    for (int d = 32; d >= 1; d >>= 1) { loss += __shfl_xor(loss, d); vld += __shfl_xor(vld, d); }
    if ((threadIdx.x & 63) == 0) { atomicAdd(&acc[0], loss); atomicAdd(&acc[1], vld); }
}

__global__ void k_final(const float* __restrict__ acc, float* __restrict__ out) {
    if (threadIdx.x == 0) out[0] = acc[0] / fmaxf(acc[1], 1.0f);
}

__global__ void k_sentinel(float* __restrict__ out) {
    if (threadIdx.x == 0) out[0] = -12345.0f;   // signals: ws too small
}

// ================= fallback path (round-4 exact, needs only 4MB+64) =================
__global__ __launch_bounds__(1024, 4) void k_main3(const unsigned short* __restrict__ xb,
                                                   const int* __restrict__ tg,
                                                   float* __restrict__ acc_g) {
    __shared__ __align__(16) unsigned short As[16 * AST_];
    __shared__ float sm[16][16][8];
    const int tid  = threadIdx.x;
    const int wave = tid >> 6, lane = tid & 63;
    const int n16  = lane & 15, quad = lane >> 4;
    const int rowBase = blockIdx.x * 16;
    {
        int row = tid >> 6, c = tid & 63;
        *(uint4*)&As[row * AST_ + c * 8] =
            *(const uint4*)(xb + (size_t)(rowBase + row) * D_ + c * 8);
    }
    int ir[4], tr[4];
    #pragma unroll
    for (int r = 0; r < 4; ++r) { ir[r] = rowBase + quad * 4 + r; tr[r] = tg[ir[r]]; }
    float m_p[4], S_p[4], m_n[4], S_n[4], mnp[4], mxn[4], sc[4];
    #pragma unroll
    for (int r = 0; r < 4; ++r) {
        m_p[r] = 0.f; S_p[r] = 0.f; m_n[r] = 0.f; S_n[r] = 0.f;
        mnp[r] = 2.0f; mxn[r] = -2.0f; sc[r] = 0.f;
    }
    __syncthreads();
    const unsigned short* Af = &As[n16 * AST_ + quad * 8];
    #pragma unroll 1
    for (int t = wave; t < N_ / 16; t += 16) {
        const int jcol = t * 16 + n16;
        const int tc = tg[jcol];
        const bf16x8* bp = (const bf16x8*)(xb + (size_t)jcol * D_ + quad * 8);
        bf16x8 bf[16];
        #pragma unroll
        for (int kk = 0; kk < 16; ++kk) bf[kk] = bp[kk * 4];
        f32x4 a0 = {0.f, 0.f, 0.f, 0.f}, a1 = {0.f, 0.f, 0.f, 0.f};
        #pragma unroll
        for (int kk = 0; kk < 8; ++kk) {
            bf16x8 af0 = *(const bf16x8*)(Af + (2 * kk) * 32);
            bf16x8 af1 = *(const bf16x8*)(Af + (2 * kk + 1) * 32);
            a0 = __builtin_amdgcn_mfma_f32_16x16x32_bf16(af0, bf[2 * kk],     a0, 0, 0, 0);
            a1 = __builtin_amdgcn_mfma_f32_16x16x32_bf16(af1, bf[2 * kk + 1], a1, 0, 0, 0);
        }
        #pragma unroll
        for (int r = 0; r < 4; ++r) {
            float s = a0[r] + a1[r];
            bool samec = (tr[r] == tc);
            bool posm  = samec && (jcol != ir[r]);
            float tp = posm  ? pos_term(s) : MASKT_;
            float tn = samec ? MASKT_ : neg_term(s);
            float mm = fmaxf(m_p[r], tp);
            S_p[r] = S_p[r] * __expf(m_p[r] - mm) + __expf(tp - mm); m_p[r] = mm;
            mm = fmaxf(m_n[r], tn);
            S_n[r] = S_n[r] * __expf(m_n[r] - mm) + __expf(tn - mm); m_n[r] = mm;
            sc[r] += samec ? 1.0f : 0.0f;
            mnp[r] = fminf(mnp[r], posm ? s : 2.0f);
            mxn[r] = fmaxf(mxn[r], samec ? -2.0f : s);
        }
    }
    #pragma unroll
    for (int r = 0; r < 4; ++r) {
        #pragma unroll
        for (int d = 1; d <= 8; d <<= 1) {
            lse_merge(__shfl_xor(m_p[r], d), __shfl_xor(S_p[r], d), m_p[r], S_p[r]);
            lse_merge(__shfl_xor(m_n[r], d), __shfl_xor(S_n[r], d), m_n[r], S_n[r]);
            mnp[r] = fminf(mnp[r], __shfl_xor(mnp[r], d));
            mxn[r] = fmaxf(mxn[r], __shfl_xor(mxn[r], d));
            sc[r] += __shfl_xor(sc[r], d);
        }
    }
    if (n16 == 0) {
        #pragma unroll
        for (int r = 0; r < 4; ++r) {
            float* q = sm[wave][quad * 4 + r];
            q[0] = m_p[r]; q[1] = S_p[r]; q[2] = m_n[r]; q[3] = S_n[r];
            q[4] = mnp[r]; q[5] = mxn[r]; q[6] = sc[r];
        }
    }
    __syncthreads();
    if (tid < 64) {
        const int L = tid & 15;
        float m_p2 = 0.f, S_p2 = 0.f, m_n2 = 0.f, S_n2 = 0.f;
        float mnp2 = 2.0f, mxn2 = -2.0f, sct = 0.f;
        #pragma unroll
        for (int w = 0; w < 16; ++w) {
            const float* q = sm[w][L];
            lse_merge(q[0], q[1], m_p2, S_p2);
            lse_merge(q[2], q[3], m_n2, S_n2);
            mnp2 = fminf(mnp2, q[4]); mxn2 = fmaxf(mxn2, q[5]);
            sct += q[6];
        }
        float loss = 0.f, vld = 0.f;
        float np2 = sct - 1.0f, nn2 = (float)N_ - sct;
        if (tid < 16 && np2 > 0.5f && nn2 > 0.5f) {
            if (np2 > 1.5f) {
                float t1 = pos_term(mnp2), t2 = 2.0f * t1;
                float mm = fmaxf(m_p2, t2);
                S_p2 = S_p2 * __expf(m_p2 - mm) + __expf(t2 - mm) - __expf(t1 - mm);
                m_p2 = mm;
            }
            if (nn2 > 1.5f) {
                float t1 = neg_term(mxn2), t2 = 2.0f * t1;
                float mm = fmaxf(m_n2, t2);
                S_n2 = S_n2 * __expf(m_n2 - mm) + __expf(t2 - mm) - __expf(t1 - mm);
                m_n2 = mm;
            }
            float z = (m_p2 + __logf(S_p2)) + (m_n2 + __logf(S_n2));
            loss = fmaxf(z, 0.0f) + log1pf(__expf(-fabsf(z)));
            vld = 1.0f;
        }
        #pragma unroll
        for (int d = 32; d >= 1; d >>= 1) {
            loss += __shfl_xor(loss, d); vld += __shfl_xor(vld, d);
        }
        if (tid == 0) { atomicAdd(&acc_g[0], loss); atomicAdd(&acc_g[1], vld); }
    }
}

extern "C" void kernel_launch(void* const* d_in, const int* in_sizes, int n_in,
                              void* d_out, int out_size, void* d_ws, size_t ws_size,
                              hipStream_t stream) {
    const float* in = (const float*)d_in[0];
    const int*   tg = (const int*)d_in[1];
    constexpr size_t MB = 1024 * 1024;
    unsigned short* xb = (unsigned short*)d_ws;

    if (ws_size >= 5 * MB + 64) {
        float* part = (float*)((char*)d_ws + 4 * MB);
        float* acc  = (float*)((char*)d_ws + 5 * MB);
        hipLaunchKernelGGL(k_norm,    dim3(N_ / 4),   dim3(256), 0, stream, in, xb, acc);
        hipLaunchKernelGGL(k_mainB,   dim3(64 * CCH_), dim3(256), 0, stream, xb, tg, part);
        hipLaunchKernelGGL(k_reduceB, dim3(N_ / 256), dim3(256), 0, stream, part, acc);
        hipLaunchKernelGGL(k_final,   dim3(1),        dim3(64),  0, stream, acc, (float*)d_out);
    } else if (ws_size >= 4 * MB + 64) {
        float* acc = (float*)((char*)d_ws + 4 * MB);
        hipLaunchKernelGGL(k_norm,  dim3(N_ / 4),  dim3(256),  0, stream, in, xb, acc);
        hipLaunchKernelGGL(k_main3, dim3(N_ / 16), dim3(1024), 0, stream, xb, tg, acc);
        hipLaunchKernelGGL(k_final, dim3(1),       dim3(64),   0, stream, acc, (float*)d_out);
    } else {
        hipLaunchKernelGGL(k_sentinel, dim3(1), dim3(64), 0, stream, (float*)d_out);
    }
}